// Round 1
// baseline (15.752 us; speedup 1.0000x reference)
//
#include <hip/hip_runtime.h>

// out[b, p, :] = sequence[b, positions[b, p], :]
// B=8, S=8192, D=1024, P=1024, fp32. Pure memory-bound row gather.
// One 256-thread block per output row; each thread copies one float4
// (256 * 16B = 4KB = one D=1024 fp32 row). Fully coalesced both sides.

#ifndef GATHER_B
#define GATHER_B 8
#define GATHER_S 8192
#define GATHER_D 1024
#define GATHER_P 1024
#endif

__global__ __launch_bounds__(256) void OnehotGather_35502199668766_kernel(
    const float4* __restrict__ seq,   // (B, S, D/4) float4
    const int* __restrict__ pos,      // (B, P) int32
    float4* __restrict__ out)         // (B, P, D/4) float4
{
    constexpr int D4 = GATHER_D / 4;          // 256 float4 per row
    const int row = blockIdx.x;               // [0, B*P)
    const int b = row >> 10;                  // row / P, P=1024
    const int idx = pos[row];                 // gathered source row

    const float4* __restrict__ src =
        seq + ((size_t)b * GATHER_S + (size_t)idx) * D4;
    float4* __restrict__ dst = out + (size_t)row * D4;

    // blockDim.x == 256 == D4: exactly one float4 per thread.
    const int t = threadIdx.x;
    dst[t] = src[t];
}

extern "C" void kernel_launch(void* const* d_in, const int* in_sizes, int n_in,
                              void* d_out, int out_size, void* d_ws, size_t ws_size,
                              hipStream_t stream) {
    const float4* seq = (const float4*)d_in[0];
    const int* pos = (const int*)d_in[1];
    float4* out = (float4*)d_out;

    const int n_rows = in_sizes[1];           // B*P = 8192
    dim3 grid(n_rows);
    dim3 block(256);
    OnehotGather_35502199668766_kernel<<<grid, block, 0, stream>>>(seq, pos, out);
}

// Round 2
// 14.398 us; speedup vs baseline: 1.0940x; 1.0940x over previous
//
#include <hip/hip_runtime.h>

// out[b, p, :] = sequence[b, positions[b, p], :]
// B=8, S=8192, D=1024, P=1024, fp32. Pure memory-bound row gather.
//
// R2: ILP-8 restructure. 8 rows per 256-thread block (32 KB/block, 1024
// blocks). Each thread: 8 wave-uniform position loads (-> s_load), then 8
// independent float4 gather loads (8 outstanding VMEM ops to hide ~900cy
// HBM latency), then 8 nontemporal float4 stores (output is never re-read;
// keep it out of L2).

#define GATHER_B 8
#define GATHER_S 8192
#define GATHER_D 1024
#define GATHER_P 1024

typedef float f4 __attribute__((ext_vector_type(4)));

__global__ __launch_bounds__(256) void OnehotGather_35502199668766_kernel(
    const f4* __restrict__ seq,   // (B, S, D/4)
    const int* __restrict__ pos,  // (B, P) int32
    f4* __restrict__ out)         // (B, P, D/4)
{
    constexpr int D4 = GATHER_D / 4;   // 256 float4 per row
    constexpr int RPB = 8;             // rows per block

    const int row0 = blockIdx.x * RPB;         // P=1024 % 8 == 0 -> same batch
    const int b = row0 >> 10;                  // row / P
    const int t = threadIdx.x;

    const f4* __restrict__ seq_b = seq + (size_t)b * GATHER_S * D4;

    // Wave-uniform indices -> scalar loads.
    int idx[RPB];
#pragma unroll
    for (int r = 0; r < RPB; ++r) idx[r] = pos[row0 + r];

    // 8 independent gather loads in flight.
    f4 v[RPB];
#pragma unroll
    for (int r = 0; r < RPB; ++r) v[r] = seq_b[(size_t)idx[r] * D4 + t];

    f4* __restrict__ dst = out + (size_t)row0 * D4 + t;
#pragma unroll
    for (int r = 0; r < RPB; ++r)
        __builtin_nontemporal_store(v[r], dst + (size_t)r * D4);
}

extern "C" void kernel_launch(void* const* d_in, const int* in_sizes, int n_in,
                              void* d_out, int out_size, void* d_ws, size_t ws_size,
                              hipStream_t stream) {
    const f4* seq = (const f4*)d_in[0];
    const int* pos = (const int*)d_in[1];
    f4* out = (f4*)d_out;

    const int n_rows = in_sizes[1];            // B*P = 8192
    dim3 grid(n_rows / 8);                     // 1024 blocks
    dim3 block(256);
    OnehotGather_35502199668766_kernel<<<grid, block, 0, stream>>>(seq, pos, out);
}

// Round 3
// 13.787 us; speedup vs baseline: 1.1425x; 1.0443x over previous
//
#include <hip/hip_runtime.h>

// out[b, p, :] = sequence[b, positions[b, p], :]
// B=8, S=8192, D=1024, P=1024, fp32. Pure memory-bound row gather.
//
// R3: ILP-16, 512 blocks (2 blocks/CU). Dispatch-count reduction is what
// paid off in R2 (8192->1024 blocks); push further. Each 256-thread block
// handles 16 rows (64 KB). 16 independent gather loads in flight per thread,
// then 16 nontemporal float4 stores (output never re-read; keep the write
// stream from evicting gathered seq rows out of L2/L3).

#define GATHER_B 8
#define GATHER_S 8192
#define GATHER_D 1024
#define GATHER_P 1024

typedef float f4 __attribute__((ext_vector_type(4)));

__global__ __launch_bounds__(256) void OnehotGather_35502199668766_kernel(
    const f4* __restrict__ seq,   // (B, S, D/4)
    const int* __restrict__ pos,  // (B, P) int32
    f4* __restrict__ out)         // (B, P, D/4)
{
    constexpr int D4 = GATHER_D / 4;   // 256 float4 per row
    constexpr int RPB = 16;            // rows per block

    const int row0 = blockIdx.x * RPB;         // 16 | P -> block stays in one batch
    const int b = row0 >> 10;                  // row / P
    const int t = threadIdx.x;

    const f4* __restrict__ seq_b = seq + (size_t)b * GATHER_S * D4;

    // Wave-uniform indices (broadcast loads).
    int idx[RPB];
#pragma unroll
    for (int r = 0; r < RPB; ++r) idx[r] = pos[row0 + r];

    // 16 independent gather loads in flight.
    f4 v[RPB];
#pragma unroll
    for (int r = 0; r < RPB; ++r) v[r] = seq_b[(size_t)idx[r] * D4 + t];

    f4* __restrict__ dst = out + (size_t)row0 * D4 + t;
#pragma unroll
    for (int r = 0; r < RPB; ++r)
        __builtin_nontemporal_store(v[r], dst + (size_t)r * D4);
}

extern "C" void kernel_launch(void* const* d_in, const int* in_sizes, int n_in,
                              void* d_out, int out_size, void* d_ws, size_t ws_size,
                              hipStream_t stream) {
    const f4* seq = (const f4*)d_in[0];
    const int* pos = (const int*)d_in[1];
    f4* out = (f4*)d_out;

    const int n_rows = in_sizes[1];            // B*P = 8192
    dim3 grid(n_rows / 16);                    // 512 blocks
    dim3 block(256);
    OnehotGather_35502199668766_kernel<<<grid, block, 0, stream>>>(seq, pos, out);
}

// Round 4
// 13.724 us; speedup vs baseline: 1.1477x; 1.0046x over previous
//
#include <hip/hip_runtime.h>

// out[b, p, :] = sequence[b, positions[b, p], :]
// B=8, S=8192, D=1024, P=1024, fp32. Pure memory-bound row gather.
//
// R4: 256 blocks (exactly 1 block/CU), RPB=32 (128 KB/block). Grid-count
// reduction is the only lever that has paid (15.75 -> 14.40 -> 13.79 us
// for 8192 -> 1024 -> 512 blocks). 32 independent float4 gathers in flight
// per thread, then 32 nontemporal stores (writes never re-read; keep them
// out of L2 so gathered seq rows stay cached).

#define GATHER_B 8
#define GATHER_S 8192
#define GATHER_D 1024
#define GATHER_P 1024

typedef float f4 __attribute__((ext_vector_type(4)));

__global__ __launch_bounds__(256) void OnehotGather_35502199668766_kernel(
    const f4* __restrict__ seq,   // (B, S, D/4)
    const int* __restrict__ pos,  // (B, P) int32
    f4* __restrict__ out)         // (B, P, D/4)
{
    constexpr int D4 = GATHER_D / 4;   // 256 float4 per row
    constexpr int RPB = 32;            // rows per block

    const int row0 = blockIdx.x * RPB;         // 32 | P -> block stays in one batch
    const int b = row0 >> 10;                  // row / P
    const int t = threadIdx.x;

    const f4* __restrict__ seq_b = seq + (size_t)b * GATHER_S * D4;

    // Wave-uniform indices (scalar broadcast loads).
    int idx[RPB];
#pragma unroll
    for (int r = 0; r < RPB; ++r) idx[r] = pos[row0 + r];

    // 32 independent gather loads in flight (128 VGPRs of payload).
    f4 v[RPB];
#pragma unroll
    for (int r = 0; r < RPB; ++r) v[r] = seq_b[(size_t)idx[r] * D4 + t];

    f4* __restrict__ dst = out + (size_t)row0 * D4 + t;
#pragma unroll
    for (int r = 0; r < RPB; ++r)
        __builtin_nontemporal_store(v[r], dst + (size_t)r * D4);
}

extern "C" void kernel_launch(void* const* d_in, const int* in_sizes, int n_in,
                              void* d_out, int out_size, void* d_ws, size_t ws_size,
                              hipStream_t stream) {
    const f4* seq = (const f4*)d_in[0];
    const int* pos = (const int*)d_in[1];
    f4* out = (f4*)d_out;

    const int n_rows = in_sizes[1];            // B*P = 8192
    dim3 grid(n_rows / 32);                    // 256 blocks, 1 per CU
    dim3 block(256);
    OnehotGather_35502199668766_kernel<<<grid, block, 0, stream>>>(seq, pos, out);
}